// Round 8
// baseline (1169.575 us; speedup 1.0000x reference)
//
#include <hip/hip_runtime.h>
#include <hip/hip_bf16.h>
#include <cstdint>
#include <cstddef>

#define Bsz  256
#define Tn   4096
#define In   8
#define Hn   32
#define TGTn 8

// sigmoid(p) = 1/(1+exp2(ALPHA*p)); tanh path: exp(2y) = exp2(BETA*y)
#define ALPHA (-1.44269504088896341f)
#define BETA  ( 2.88539008177792682f)

typedef float v2f __attribute__((ext_vector_type(2)));

__device__ __forceinline__ v2f pk_fma(v2f a, v2f b, v2f c) {
    return __builtin_elementwise_fma(a, b, c);
}

#if __has_builtin(__builtin_amdgcn_exp2f)
__device__ __forceinline__ float exp2f_fast(float x) { return __builtin_amdgcn_exp2f(x); }
#else
__device__ __forceinline__ float exp2f_fast(float x) { return __expf(x * 0.69314718056f); }
#endif
__device__ __forceinline__ float rcpf(float x) { return __builtin_amdgcn_rcpf(x); }

// DPP rotate within 16-lane rows; convention handled by probing.
template<int N>
__device__ __forceinline__ float dpp_ror(float x) {
    int xi = __float_as_int(x);
    int r = __builtin_amdgcn_update_dpp(xi, xi, 0x120 + N, 0xF, 0xF, false);
    return __int_as_float(r);
}

// x_l + x_{l^32} in every lane (hazards managed by compiler builtin).
__device__ __forceinline__ float half_sum(float x) {
    auto r = __builtin_amdgcn_permlane32_swap(__float_as_int(x), __float_as_int(x),
                                              false, false);
    return __int_as_float((int)r[0]) + __int_as_float((int)r[1]);
}

// Unordered pair {f(lane&15), f(16+(lane&15))}; caller probes slot order.
__device__ __forceinline__ void row16_pair(float x, float& a_out, float& b_out) {
    auto r = __builtin_amdgcn_permlane16_swap(__float_as_int(x), __float_as_int(x),
                                              false, false);
    a_out = __int_as_float((int)r[0]);
    b_out = __int_as_float((int)r[1]);
}

// Array-based butterfly — init-time probe only; must match the macro's H-builds.
__device__ __forceinline__ void gather16_probe(float v, v2f H[8]) {
    v2f G0; G0.x = v;                G0.y = dpp_ror<1>(v);
    v2f G1; G1.x = dpp_ror<2>(G0.x); G1.y = dpp_ror<2>(G0.y);
    v2f G2; G2.x = dpp_ror<4>(G0.x); G2.y = dpp_ror<4>(G0.y);
    v2f G3; G3.x = dpp_ror<4>(G1.x); G3.y = dpp_ror<4>(G1.y);
    v2f G4; G4.x = dpp_ror<8>(G0.x); G4.y = dpp_ror<8>(G0.y);
    v2f G5; G5.x = dpp_ror<8>(G1.x); G5.y = dpp_ror<8>(G1.y);
    v2f G6; G6.x = dpp_ror<8>(G2.x); G6.y = dpp_ror<8>(G2.y);
    v2f G7; G7.x = dpp_ror<8>(G3.x); G7.y = dpp_ror<8>(G3.y);
    H[0]=G0; H[1]=G1; H[2]=G2; H[3]=G3; H[4]=G4; H[5]=G5; H[6]=G6; H[7]=G7;
}

// W = w_ih @ E : [96,8], pre-scaled: rows 0..63 (r,z) by ALPHA, 64..95 (n) by BETA
__global__ void fuse_wih_kernel(const float* __restrict__ w_ih,
                                const float* __restrict__ E,
                                float* __restrict__ Wf) {
    int tid = threadIdx.x;                // 768 threads
    int g = tid >> 3, i = tid & 7;
    float acc = 0.f;
#pragma unroll
    for (int k = 0; k < Hn; ++k)
        acc = fmaf(w_ih[g * Hn + k], E[k * In + i], acc);
    Wf[g * In + i] = acc * (g < 2 * Hn ? ALPHA : BETA);
}

// x-preactivations for the next step from the uniform slot pair (XA,XB).
// Biases (incl. ALPHA/BETA scaling) folded into the chain inits.
#define PREACT(XA, XB)                                                               \
  {                                                                                  \
    v2f p0 = v2f{XA.x, XA.y}, p1 = v2f{XA.z, XA.w};                                  \
    v2f p2 = v2f{XB.x, XB.y}, p3 = v2f{XB.z, XB.w};                                  \
    v2f dr = pk_fma(p0, wxr0, pk_fma(p1, wxr1, pk_fma(p2, wxr2, pk_fma(p3, wxr3, biasr)))); \
    axr = dr.x + dr.y;                                                               \
    v2f dz = pk_fma(p0, wxz0, pk_fma(p1, wxz1, pk_fma(p2, wxz2, pk_fma(p3, wxz3, biasz)))); \
    axz = dz.x + dz.y;                                                               \
    v2f dn = pk_fma(p0, wxn0, pk_fma(p1, wxn1, pk_fma(p2, wxn2, pk_fma(p3, wxn3, biasn)))); \
    cxn = dn.x + dn.y;                                                               \
  }

// One GRU step. XNA/XNB: slot pair holding x[s+1]; XRA/XRB: slot pair freed
// this step (refilled with x[s+4] when DO_REFILL).
#define GRU_STEP(XNA, XNB, XRA, XRB, DO_REFILL)                                      \
  {                                                                                  \
    v2f ar0 = pk_fma(H0, whr0, pk_fma(H2, whr2, pk_fma(H4, whr4, H6 * whr6)));       \
    v2f ar1 = pk_fma(H1, whr1, pk_fma(H3, whr3, pk_fma(H5, whr5, H7 * whr7)));       \
    v2f az0 = pk_fma(H0, whz0, pk_fma(H2, whz2, pk_fma(H4, whz4, H6 * whz6)));       \
    v2f az1 = pk_fma(H1, whz1, pk_fma(H3, whz3, pk_fma(H5, whz5, H7 * whz7)));       \
    v2f an0 = pk_fma(H0, whn0, pk_fma(H2, whn2, pk_fma(H4, whn4, H6 * whn6)));       \
    v2f an1 = pk_fma(H1, whn1, pk_fma(H3, whn3, pk_fma(H5, whn5, H7 * whn7)));       \
    v2f art = ar0 + ar1;                                                             \
    v2f azt = az0 + az1;                                                             \
    v2f ant = an0 + an1;                                                             \
    float cr  = half_sum(art.x + art.y) + axr;                                       \
    float cz  = half_sum(azt.x + azt.y) + axz;                                       \
    float chn = half_sum(ant.x + ant.y) + bhnB;                                      \
    float r = rcpf(1.f + exp2f_fast(cr));                                            \
    float z = rcpf(1.f + exp2f_fast(cz));                                            \
    float e = exp2f_fast(__builtin_fmaf(r, chn, cxn));                               \
    float u = rcpf(e + 1.f);                                                         \
    float n = __builtin_fmaf(-2.f, u, 1.f);                                          \
    hj = __builtin_fmaf(z, hj - n, n);                                               \
    float va, vb;                                                                    \
    row16_pair(hj, va, vb);                                                          \
    float gv = pick_a ? va : vb;          /* = h[grp*16 + (lane&15)] */              \
    H0 = v2f{gv, dpp_ror<1>(gv)};                                                    \
    H1 = v2f{dpp_ror<2>(H0.x), dpp_ror<2>(H0.y)};                                    \
    H2 = v2f{dpp_ror<4>(H0.x), dpp_ror<4>(H0.y)};                                    \
    H3 = v2f{dpp_ror<4>(H1.x), dpp_ror<4>(H1.y)};                                    \
    H4 = v2f{dpp_ror<8>(H0.x), dpp_ror<8>(H0.y)};                                    \
    H5 = v2f{dpp_ror<8>(H1.x), dpp_ror<8>(H1.y)};                                    \
    H6 = v2f{dpp_ror<8>(H2.x), dpp_ror<8>(H2.y)};                                    \
    H7 = v2f{dpp_ror<8>(H3.x), dpp_ror<8>(H3.y)};                                    \
    latb[j] = hj;                                                                    \
    latb += Hn;                           /* uniform -> SALU */                      \
    PREACT(XNA, XNB)                                                                 \
    if (DO_REFILL) {                                                                 \
        XRA = *(const float4*)(refp);                                                \
        XRB = *(const float4*)(refp + 4);                                            \
        refp += In;                       /* uniform -> SALU */                      \
    }                                                                                \
  }

#define KEEP(v) asm volatile("" : "+v"(v))
__attribute__((amdgpu_flat_work_group_size(64, 64), amdgpu_waves_per_eu(1, 1)))
__global__ void gru_kernel(const float* __restrict__ x,     // [B,T,8]
                           const float* __restrict__ Wf,    // [96,8] scaled w_ih@E
                           const float* __restrict__ w_hh,  // [96,32]
                           const float* __restrict__ b_ih,  // [96]
                           const float* __restrict__ b_hh,  // [96]
                           float* __restrict__ latents) {   // [B,T,32]
    const int lane = threadIdx.x & 63;
    const int grp  = lane >> 5;     // K-half this lane accumulates (h-dots only)
    const int j    = lane & 31;     // hidden row this lane produces
    const int r16  = lane & 15;
    const int b    = blockIdx.x;

    // ---- probe hardware permutation conventions ----
    int sidx[16];
    {
        v2f P[8];
        gather16_probe((float)r16, P);
#pragma unroll
        for (int q = 0; q < 8; ++q) {
            sidx[2*q]   = (int)P[q].x;
            sidx[2*q+1] = (int)P[q].y;
        }
    }
    bool pick_a;
    {
        float va, vb;
        row16_pair((float)j, va, vb);
        pick_a = ((int)va == grp * 16 + r16);
    }

    // ---- recurrent weights (probed order), pre-scaled by ALPHA/BETA ----
    v2f whr0, whr1, whr2, whr3, whr4, whr5, whr6, whr7;
    v2f whz0, whz1, whz2, whz3, whz4, whz5, whz6, whz7;
    v2f whn0, whn1, whn2, whn3, whn4, whn5, whn6, whn7;
#define LOADW(Q)                                                                     \
    {                                                                                \
        const int c0 = grp * 16 + sidx[2*Q], c1 = grp * 16 + sidx[2*Q+1];            \
        whr##Q = v2f{ALPHA * w_hh[(0*Hn + j)*Hn + c0], ALPHA * w_hh[(0*Hn + j)*Hn + c1]}; \
        whz##Q = v2f{ALPHA * w_hh[(1*Hn + j)*Hn + c0], ALPHA * w_hh[(1*Hn + j)*Hn + c1]}; \
        whn##Q = v2f{BETA  * w_hh[(2*Hn + j)*Hn + c0], BETA  * w_hh[(2*Hn + j)*Hn + c1]}; \
        KEEP(whr##Q); KEEP(whz##Q); KEEP(whn##Q);                                    \
    }
    LOADW(0) LOADW(1) LOADW(2) LOADW(3) LOADW(4) LOADW(5) LOADW(6) LOADW(7)
#undef LOADW

    // ---- full-8 input weights (Wf already ALPHA/BETA-scaled) ----
    v2f wxr0 = *(const v2f*)&Wf[(0*Hn+j)*In + 0], wxr1 = *(const v2f*)&Wf[(0*Hn+j)*In + 2];
    v2f wxr2 = *(const v2f*)&Wf[(0*Hn+j)*In + 4], wxr3 = *(const v2f*)&Wf[(0*Hn+j)*In + 6];
    v2f wxz0 = *(const v2f*)&Wf[(1*Hn+j)*In + 0], wxz1 = *(const v2f*)&Wf[(1*Hn+j)*In + 2];
    v2f wxz2 = *(const v2f*)&Wf[(1*Hn+j)*In + 4], wxz3 = *(const v2f*)&Wf[(1*Hn+j)*In + 6];
    v2f wxn0 = *(const v2f*)&Wf[(2*Hn+j)*In + 0], wxn1 = *(const v2f*)&Wf[(2*Hn+j)*In + 2];
    v2f wxn2 = *(const v2f*)&Wf[(2*Hn+j)*In + 4], wxn3 = *(const v2f*)&Wf[(2*Hn+j)*In + 6];
    KEEP(wxr0); KEEP(wxr1); KEEP(wxr2); KEEP(wxr3);
    KEEP(wxz0); KEEP(wxz1); KEEP(wxz2); KEEP(wxz3);
    KEEP(wxn0); KEEP(wxn1); KEEP(wxn2); KEEP(wxn3);

    // biases folded into x-chain inits (scaled); chn's recurrent bias separate
    v2f biasr = v2f{ALPHA * (b_ih[j]      + b_hh[j]),      0.f};
    v2f biasz = v2f{ALPHA * (b_ih[Hn + j] + b_hh[Hn + j]), 0.f};
    v2f biasn = v2f{BETA  *  b_ih[2*Hn + j],               0.f};
    float bhnB = BETA * b_hh[2*Hn + j];
    KEEP(biasr); KEEP(biasz); KEEP(biasn); KEEP(bhnB);

    const float* xb = x + (size_t)b * Tn * In;
    float* latb     = latents + (size_t)b * Tn * Hn;   // uniform; +j at store
    const float* refp = xb + 4 * In;                   // next refill = x[4]

    float hj = 0.f;
    v2f H0{0.f,0.f}, H1{0.f,0.f}, H2{0.f,0.f}, H3{0.f,0.f},
        H4{0.f,0.f}, H5{0.f,0.f}, H6{0.f,0.f}, H7{0.f,0.f};

    // ---- 4-deep uniform x ring (full 8 floats/step as float4 pairs) ----
    float4 a0 = *(const float4*)&xb[0*In],     b0 = *(const float4*)&xb[0*In + 4];
    float4 a1 = *(const float4*)&xb[1*In],     b1 = *(const float4*)&xb[1*In + 4];
    float4 a2 = *(const float4*)&xb[2*In],     b2 = *(const float4*)&xb[2*In + 4];
    float4 a3 = *(const float4*)&xb[3*In],     b3 = *(const float4*)&xb[3*In + 4];

    float axr, axz, cxn;
    PREACT(a0, b0)                      // pre-activations for step 0

    // main loop: 1023 groups of 4 steps (s = 0..4091), refills x[s+4]
#pragma unroll 1
    for (int s0 = 0; s0 < Tn - 4; s0 += 4) {
        GRU_STEP(a1, b1, a0, b0, true)
        GRU_STEP(a2, b2, a1, b1, true)
        GRU_STEP(a3, b3, a2, b2, true)
        GRU_STEP(a0, b0, a3, b3, true)
    }
    // epilogue: steps 4092..4095 (slots hold x[4092..4095]); no refills.
    // (final PREACT reads a stale slot; its result is never consumed)
    GRU_STEP(a1, b1, a0, b0, false)
    GRU_STEP(a2, b2, a1, b1, false)
    GRU_STEP(a3, b3, a2, b2, false)
    GRU_STEP(a0, b0, a3, b3, false)
}
#undef KEEP

// outputs[b,t,o] = sum_h latents[b,t,h] * E[h,o]
__global__ void decode_kernel(const float* __restrict__ lat,
                              const float* __restrict__ E,
                              float* __restrict__ out) {
    __shared__ float ldsE[Hn * TGTn];
    int tid = threadIdx.x;
    if (tid < Hn * TGTn) ldsE[tid] = E[tid];
    __syncthreads();
    size_t idx = (size_t)blockIdx.x * 256 + tid;   // over B*T*8
    int o      = (int)(idx & (TGTn - 1));
    size_t row = idx >> 3;
    const float* lrow = lat + row * Hn;
    float acc = 0.f;
#pragma unroll
    for (int h = 0; h < Hn; ++h)
        acc = fmaf(lrow[h], ldsE[h * TGTn + o], acc);
    out[idx] = acc;
}

extern "C" void kernel_launch(void* const* d_in, const int* in_sizes, int n_in,
                              void* d_out, int out_size, void* d_ws, size_t ws_size,
                              hipStream_t stream) {
    const float* x    = (const float*)d_in[0];
    const float* E    = (const float*)d_in[1];
    const float* w_ih = (const float*)d_in[2];
    const float* w_hh = (const float*)d_in[3];
    const float* b_ih = (const float*)d_in[4];
    const float* b_hh = (const float*)d_in[5];

    float* out = (float*)d_out;                          // [B,T,8]
    float* lat = out + (size_t)Bsz * Tn * TGTn;          // [B,T,32]
    float* Wf  = (float*)d_ws;                           // [96,8]

    fuse_wih_kernel<<<1, 768, 0, stream>>>(w_ih, E, Wf);
    gru_kernel<<<Bsz, 64, 0, stream>>>(x, Wf, w_hh, b_ih, b_hh, lat);
    decode_kernel<<<(Bsz * Tn * TGTn) / 256, 256, 0, stream>>>(lat, E, out);
}